// Round 1
// baseline (7396.897 us; speedup 1.0000x reference)
//
#include <hip/hip_runtime.h>

#define D 64
#define EPS 1e-12f

__device__ __forceinline__ float wave_sum(float v) {
#pragma unroll
  for (int off = 32; off > 0; off >>= 1) v += __shfl_xor(v, off, 64);
  return v;
}

// v[d] = sum_j att_mat[d, j] * att_agg[j]
__global__ void compute_v_kernel(const float* __restrict__ att_mat,
                                 const float* __restrict__ att_agg,
                                 float* __restrict__ v) {
  int d = threadIdx.x;
  float s = 0.f;
#pragma unroll
  for (int j = 0; j < D; ++j) s += att_mat[d * D + j] * att_agg[j];
  v[d] = s;
}

// u_k = emb * sigmoid(emb @ W_k + b_k) for k=0..3 ; also write copies to acc slots
__global__ __launch_bounds__(256) void gating4_kernel(
    const float* __restrict__ emb, const float* __restrict__ W,
    const float* __restrict__ B, float* __restrict__ u0, float* __restrict__ u1,
    float* __restrict__ u2, float* __restrict__ u3, float* __restrict__ a0,
    float* __restrict__ a1, float* __restrict__ a2, float* __restrict__ a3,
    int nrows) {
  __shared__ float sW[4 * D * D];  // 64 KiB
  for (int i = threadIdx.x; i < 4 * D * D; i += blockDim.x) sW[i] = W[i];
  __syncthreads();
  int lane = threadIdx.x & 63;
  int wid = (blockIdx.x * blockDim.x + threadIdx.x) >> 6;
  int nw = (gridDim.x * blockDim.x) >> 6;
  float b0 = B[0 * D + lane], b1 = B[1 * D + lane];
  float b2 = B[2 * D + lane], b3 = B[3 * D + lane];
  for (int r = wid; r < nrows; r += nw) {
    float e = emb[r * D + lane];
    float y0 = b0, y1 = b1, y2 = b2, y3 = b3;
#pragma unroll 16
    for (int j = 0; j < D; ++j) {
      float ej = __shfl(e, j, 64);
      y0 += ej * sW[0 * D * D + j * D + lane];
      y1 += ej * sW[1 * D * D + j * D + lane];
      y2 += ej * sW[2 * D * D + j * D + lane];
      y3 += ej * sW[3 * D * D + j * D + lane];
    }
    float o0 = e / (1.f + __expf(-y0));
    float o1 = e / (1.f + __expf(-y1));
    float o2 = e / (1.f + __expf(-y2));
    float o3 = e / (1.f + __expf(-y3));
    int idx = r * D + lane;
    u0[idx] = o0; a0[idx] = o0;
    u1[idx] = o1; a1[idx] = o1;
    u2[idx] = o2; a2[idx] = o2;
    u3[idx] = o3; a3[idx] = o3;
  }
}

// sg_k = x * sigmoid(x @ W_k + b_k) for k=0..2
__global__ __launch_bounds__(256) void sgating3_kernel(
    const float* __restrict__ x, const float* __restrict__ W,
    const float* __restrict__ B, float* __restrict__ o0f,
    float* __restrict__ o1f, float* __restrict__ o2f, int nrows) {
  __shared__ float sW[3 * D * D];  // 48 KiB
  for (int i = threadIdx.x; i < 3 * D * D; i += blockDim.x) sW[i] = W[i];
  __syncthreads();
  int lane = threadIdx.x & 63;
  int wid = (blockIdx.x * blockDim.x + threadIdx.x) >> 6;
  int nw = (gridDim.x * blockDim.x) >> 6;
  float b0 = B[0 * D + lane], b1 = B[1 * D + lane], b2 = B[2 * D + lane];
  for (int r = wid; r < nrows; r += nw) {
    float e = x[r * D + lane];
    float y0 = b0, y1 = b1, y2 = b2;
#pragma unroll 16
    for (int j = 0; j < D; ++j) {
      float ej = __shfl(e, j, 64);
      y0 += ej * sW[0 * D * D + j * D + lane];
      y1 += ej * sW[1 * D * D + j * D + lane];
      y2 += ej * sW[2 * D * D + j * D + lane];
    }
    int idx = r * D + lane;
    o0f[idx] = e / (1.f + __expf(-y0));
    o1f[idx] = e / (1.f + __expf(-y1));
    o2f[idx] = e / (1.f + __expf(-y2));
  }
}

// mixed = (softmax-weighted(u0,u1,u2) + us) * 0.5
__global__ __launch_bounds__(256) void attn_mix_kernel(
    const float* __restrict__ u0, const float* __restrict__ u1,
    const float* __restrict__ u2, const float* __restrict__ us,
    const float* __restrict__ v, float* __restrict__ mixed, int nrows) {
  int lane = threadIdx.x & 63;
  int wid = (blockIdx.x * blockDim.x + threadIdx.x) >> 6;
  if (wid >= nrows) return;
  int idx = wid * D + lane;
  float e0 = u0[idx], e1 = u1[idx], e2 = u2[idx], eu = us[idx];
  float vd = v[lane];
  float w0 = wave_sum(e0 * vd);
  float w1 = wave_sum(e1 * vd);
  float w2 = wave_sum(e2 * vd);
  float m = fmaxf(w0, fmaxf(w1, w2));
  float s0 = __expf(w0 - m), s1 = __expf(w1 - m), s2 = __expf(w2 - m);
  float inv = 1.f / (s0 + s1 + s2);
  mixed[idx] = ((s0 * e0 + s1 * e1 + s2 * e2) * inv + eu) * 0.5f;
}

// out = softmax-weighted(a0,a1,a2) + 0.5*as  (as may alias out; per-element safe)
__global__ __launch_bounds__(256) void final_attn_kernel(
    const float* __restrict__ a0, const float* __restrict__ a1,
    const float* __restrict__ a2, const float* __restrict__ as,
    const float* __restrict__ v, float* __restrict__ out, int nrows) {
  int lane = threadIdx.x & 63;
  int wid = (blockIdx.x * blockDim.x + threadIdx.x) >> 6;
  if (wid >= nrows) return;
  int idx = wid * D + lane;
  float e0 = a0[idx], e1 = a1[idx], e2 = a2[idx], eu = as[idx];
  float vd = v[lane];
  float w0 = wave_sum(e0 * vd);
  float w1 = wave_sum(e1 * vd);
  float w2 = wave_sum(e2 * vd);
  float m = fmaxf(w0, fmaxf(w1, w2));
  float s0 = __expf(w0 - m), s1 = __expf(w1 - m), s2 = __expf(w2 - m);
  float inv = 1.f / (s0 + s1 + s2);
  out[idx] = (s0 * e0 + s1 * e1 + s2 * e2) * inv + 0.5f * eu;
}

// acc += x / max(||x_row||, eps)
__global__ __launch_bounds__(256) void l2acc_kernel(const float* __restrict__ x,
                                                    float* __restrict__ acc,
                                                    int nrows) {
  int lane = threadIdx.x & 63;
  int wid = (blockIdx.x * blockDim.x + threadIdx.x) >> 6;
  if (wid >= nrows) return;
  int idx = wid * D + lane;
  float xv = x[idx];
  float ss = wave_sum(xv * xv);
  float nrm = fmaxf(sqrtf(ss), EPS);
  acc[idx] += xv / nrm;
}

// out[row[e], :] += val[e] * x[col[e], :]  (atomic scatter)
__global__ __launch_bounds__(256) void spmm_atomic_kernel(
    const int* __restrict__ row, const int* __restrict__ col,
    const float* __restrict__ val, const float* __restrict__ x,
    float* __restrict__ out, int nnz) {
  int lane = threadIdx.x & 63;
  int wid = (blockIdx.x * blockDim.x + threadIdx.x) >> 6;
  int nw = (gridDim.x * blockDim.x) >> 6;
  for (int base = wid * 64; base < nnz; base += nw * 64) {
    int e = base + lane;
    int r = 0, c = 0;
    float v = 0.f;
    if (e < nnz) { r = row[e]; c = col[e]; v = val[e]; }
    int cnt = nnz - base; if (cnt > 64) cnt = 64;
    for (int i = 0; i < cnt; ++i) {
      int ri = __shfl(r, i, 64);
      int ci = __shfl(c, i, 64);
      float vi = __shfl(v, i, 64);
      float xv = x[ci * D + lane];
      atomicAdd(&out[ri * D + lane], vi * xv);
    }
  }
}

extern "C" void kernel_launch(void* const* d_in, const int* in_sizes, int n_in,
                              void* d_out, int out_size, void* d_ws,
                              size_t ws_size, hipStream_t stream) {
  const float* user_emb = (const float*)d_in[0];
  const float* item_emb = (const float*)d_in[1];
  const float* gating_w = (const float*)d_in[2];
  const float* gating_b = (const float*)d_in[3];
  const float* sgating_w = (const float*)d_in[4];
  const float* sgating_b = (const float*)d_in[5];
  const float* att_mat = (const float*)d_in[6];
  const float* att_agg = (const float*)d_in[7];
  const int* hs_row = (const int*)d_in[8];
  const int* hs_col = (const int*)d_in[9];
  const float* hs_val = (const float*)d_in[10];
  const int* hj_row = (const int*)d_in[11];
  const int* hj_col = (const int*)d_in[12];
  const float* hj_val = (const float*)d_in[13];
  const int* hp_row = (const int*)d_in[14];
  const int* hp_col = (const int*)d_in[15];
  const float* hp_val = (const float*)d_in[16];
  const int* inter_row = (const int*)d_in[17];
  const int* inter_col = (const int*)d_in[18];
  const float* inter_val = (const float*)d_in[19];

  const int U = in_sizes[0] / D;   // 100000
  const int I = in_sizes[1] / D;   // 50000
  const int NH = in_sizes[8];      // 3200000
  const int NI = in_sizes[17];     // 3000000
  const size_t UD = (size_t)U * D;
  const size_t ID = (size_t)I * D;

  float* out = (float*)d_out;
  float* final_user = out;            // also acc_simple storage
  float* acc_item = out + UD;
  float* sg0 = out + UD + ID;         // also acc_c0
  float* sg1 = sg0 + UD;              // also acc_c1
  float* sg2 = sg1 + UD;              // also acc_c2
  float* acc0 = sg0, *acc1 = sg1, *acc2 = sg2, *accS = final_user;

  float* ws = (float*)d_ws;
  float* u0 = ws;
  float* u1 = u0 + UD;
  float* u2 = u1 + UD;
  float* us = u2 + UD;
  float* mixed = us + UD;
  float* spare = mixed + UD;
  float* it_a = spare + UD;
  float* it_b = it_a + ID;
  float* v = it_b + ID;

  const int ROWB_U = (U + 3) / 4;     // wave-per-row blocks (256 thr = 4 waves)
  const int ROWB_I = (I + 3) / 4;
  const int SPMM_BLOCKS = 2048;       // 8192 waves, grid-stride

  // v = att_mat @ att_agg^T
  hipLaunchKernelGGL(compute_v_kernel, dim3(1), dim3(64), 0, stream, att_mat,
                     att_agg, v);
  // self-gating (4 channels) + init acc_c0..2 (sg slots) and acc_simple (final slot)
  hipLaunchKernelGGL(gating4_kernel, dim3(512), dim3(256), 0, stream, user_emb,
                     gating_w, gating_b, u0, u1, u2, us, acc0, acc1, acc2, accS, U);
  // acc_item = item_emb ; it_a = item_emb
  hipMemcpyAsync(acc_item, item_emb, ID * sizeof(float),
                 hipMemcpyDeviceToDevice, stream);
  hipMemcpyAsync(it_a, item_emb, ID * sizeof(float), hipMemcpyDeviceToDevice,
                 stream);

  float* it_old = it_a;
  float* it_new = it_b;

  for (int layer = 0; layer < 2; ++layer) {
    // mixed = (attn(u0,u1,u2) + us) / 2
    hipLaunchKernelGGL(attn_mix_kernel, dim3(ROWB_U), dim3(256), 0, stream, u0,
                       u1, u2, us, v, mixed, U);
    // channel 0: hs
    hipMemsetAsync(spare, 0, UD * sizeof(float), stream);
    hipLaunchKernelGGL(spmm_atomic_kernel, dim3(SPMM_BLOCKS), dim3(256), 0,
                       stream, hs_row, hs_col, hs_val, u0, spare, NH);
    hipLaunchKernelGGL(l2acc_kernel, dim3(ROWB_U), dim3(256), 0, stream, spare,
                       acc0, U);
    { float* t = u0; u0 = spare; spare = t; }
    // channel 1: hj
    hipMemsetAsync(spare, 0, UD * sizeof(float), stream);
    hipLaunchKernelGGL(spmm_atomic_kernel, dim3(SPMM_BLOCKS), dim3(256), 0,
                       stream, hj_row, hj_col, hj_val, u1, spare, NH);
    hipLaunchKernelGGL(l2acc_kernel, dim3(ROWB_U), dim3(256), 0, stream, spare,
                       acc1, U);
    { float* t = u1; u1 = spare; spare = t; }
    // channel 2: hp
    hipMemsetAsync(spare, 0, UD * sizeof(float), stream);
    hipLaunchKernelGGL(spmm_atomic_kernel, dim3(SPMM_BLOCKS), dim3(256), 0,
                       stream, hp_row, hp_col, hp_val, u2, spare, NH);
    hipLaunchKernelGGL(l2acc_kernel, dim3(ROWB_U), dim3(256), 0, stream, spare,
                       acc2, U);
    { float* t = u2; u2 = spare; spare = t; }
    // new_item = inter^T @ mixed  (rows = inter_col, cols = inter_row)
    hipMemsetAsync(it_new, 0, ID * sizeof(float), stream);
    hipLaunchKernelGGL(spmm_atomic_kernel, dim3(SPMM_BLOCKS), dim3(256), 0,
                       stream, inter_col, inter_row, inter_val, mixed, it_new,
                       NI);
    hipLaunchKernelGGL(l2acc_kernel, dim3(ROWB_I), dim3(256), 0, stream, it_new,
                       acc_item, I);
    // u_simple = inter @ it_old
    hipMemsetAsync(spare, 0, UD * sizeof(float), stream);
    hipLaunchKernelGGL(spmm_atomic_kernel, dim3(SPMM_BLOCKS), dim3(256), 0,
                       stream, inter_row, inter_col, inter_val, it_old, spare,
                       NI);
    hipLaunchKernelGGL(l2acc_kernel, dim3(ROWB_U), dim3(256), 0, stream, spare,
                       accS, U);
    { float* t = us; us = spare; spare = t; }
    // it = new_item
    { float* t = it_old; it_old = it_new; it_new = t; }
  }

  // final_user = attn(acc0,acc1,acc2) + accS/2   (in-place over accS slot)
  hipLaunchKernelGGL(final_attn_kernel, dim3(ROWB_U), dim3(256), 0, stream,
                     acc0, acc1, acc2, accS, v, final_user, U);
  // sg0..2 = self_gating(final_user, sgating_w[k], sgating_b[k])
  hipLaunchKernelGGL(sgating3_kernel, dim3(512), dim3(256), 0, stream,
                     final_user, sgating_w, sgating_b, sg0, sg1, sg2, U);
}

// Round 2
// 4401.337 us; speedup vs baseline: 1.6806x; 1.6806x over previous
//
#include <hip/hip_runtime.h>

#define D 64
#define EPS 1e-12f

__device__ __forceinline__ float wave_sum(float v) {
#pragma unroll
  for (int off = 32; off > 0; off >>= 1) v += __shfl_xor(v, off, 64);
  return v;
}

// v[d] = sum_j att_mat[d, j] * att_agg[j]
__global__ void compute_v_kernel(const float* __restrict__ att_mat,
                                 const float* __restrict__ att_agg,
                                 float* __restrict__ v) {
  int d = threadIdx.x;
  float s = 0.f;
#pragma unroll
  for (int j = 0; j < D; ++j) s += att_mat[d * D + j] * att_agg[j];
  v[d] = s;
}

// u_k = emb * sigmoid(emb @ W_k + b_k) for k=0..3 ; also write copies to acc slots
__global__ __launch_bounds__(256) void gating4_kernel(
    const float* __restrict__ emb, const float* __restrict__ W,
    const float* __restrict__ B, float* __restrict__ u0, float* __restrict__ u1,
    float* __restrict__ u2, float* __restrict__ u3, float* __restrict__ a0,
    float* __restrict__ a1, float* __restrict__ a2, float* __restrict__ a3,
    int nrows) {
  __shared__ float sW[4 * D * D];  // 64 KiB
  for (int i = threadIdx.x; i < 4 * D * D; i += blockDim.x) sW[i] = W[i];
  __syncthreads();
  int lane = threadIdx.x & 63;
  int wid = (blockIdx.x * blockDim.x + threadIdx.x) >> 6;
  int nw = (gridDim.x * blockDim.x) >> 6;
  float b0 = B[0 * D + lane], b1 = B[1 * D + lane];
  float b2 = B[2 * D + lane], b3 = B[3 * D + lane];
  for (int r = wid; r < nrows; r += nw) {
    float e = emb[r * D + lane];
    float y0 = b0, y1 = b1, y2 = b2, y3 = b3;
#pragma unroll 16
    for (int j = 0; j < D; ++j) {
      float ej = __shfl(e, j, 64);
      y0 += ej * sW[0 * D * D + j * D + lane];
      y1 += ej * sW[1 * D * D + j * D + lane];
      y2 += ej * sW[2 * D * D + j * D + lane];
      y3 += ej * sW[3 * D * D + j * D + lane];
    }
    float o0 = e / (1.f + __expf(-y0));
    float o1 = e / (1.f + __expf(-y1));
    float o2 = e / (1.f + __expf(-y2));
    float o3 = e / (1.f + __expf(-y3));
    int idx = r * D + lane;
    u0[idx] = o0; a0[idx] = o0;
    u1[idx] = o1; a1[idx] = o1;
    u2[idx] = o2; a2[idx] = o2;
    u3[idx] = o3; a3[idx] = o3;
  }
}

// sg_k = x * sigmoid(x @ W_k + b_k) for k=0..2
__global__ __launch_bounds__(256) void sgating3_kernel(
    const float* __restrict__ x, const float* __restrict__ W,
    const float* __restrict__ B, float* __restrict__ o0f,
    float* __restrict__ o1f, float* __restrict__ o2f, int nrows) {
  __shared__ float sW[3 * D * D];  // 48 KiB
  for (int i = threadIdx.x; i < 3 * D * D; i += blockDim.x) sW[i] = W[i];
  __syncthreads();
  int lane = threadIdx.x & 63;
  int wid = (blockIdx.x * blockDim.x + threadIdx.x) >> 6;
  int nw = (gridDim.x * blockDim.x) >> 6;
  float b0 = B[0 * D + lane], b1 = B[1 * D + lane], b2 = B[2 * D + lane];
  for (int r = wid; r < nrows; r += nw) {
    float e = x[r * D + lane];
    float y0 = b0, y1 = b1, y2 = b2;
#pragma unroll 16
    for (int j = 0; j < D; ++j) {
      float ej = __shfl(e, j, 64);
      y0 += ej * sW[0 * D * D + j * D + lane];
      y1 += ej * sW[1 * D * D + j * D + lane];
      y2 += ej * sW[2 * D * D + j * D + lane];
    }
    int idx = r * D + lane;
    o0f[idx] = e / (1.f + __expf(-y0));
    o1f[idx] = e / (1.f + __expf(-y1));
    o2f[idx] = e / (1.f + __expf(-y2));
  }
}

// mixed = (softmax-weighted(u0,u1,u2) + us) * 0.5
__global__ __launch_bounds__(256) void attn_mix_kernel(
    const float* __restrict__ u0, const float* __restrict__ u1,
    const float* __restrict__ u2, const float* __restrict__ us,
    const float* __restrict__ v, float* __restrict__ mixed, int nrows) {
  int lane = threadIdx.x & 63;
  int wid = (blockIdx.x * blockDim.x + threadIdx.x) >> 6;
  if (wid >= nrows) return;
  int idx = wid * D + lane;
  float e0 = u0[idx], e1 = u1[idx], e2 = u2[idx], eu = us[idx];
  float vd = v[lane];
  float w0 = wave_sum(e0 * vd);
  float w1 = wave_sum(e1 * vd);
  float w2 = wave_sum(e2 * vd);
  float m = fmaxf(w0, fmaxf(w1, w2));
  float s0 = __expf(w0 - m), s1 = __expf(w1 - m), s2 = __expf(w2 - m);
  float inv = 1.f / (s0 + s1 + s2);
  mixed[idx] = ((s0 * e0 + s1 * e1 + s2 * e2) * inv + eu) * 0.5f;
}

// out = softmax-weighted(a0,a1,a2) + 0.5*as  (as may alias out; per-element safe)
__global__ __launch_bounds__(256) void final_attn_kernel(
    const float* __restrict__ a0, const float* __restrict__ a1,
    const float* __restrict__ a2, const float* __restrict__ as,
    const float* __restrict__ v, float* __restrict__ out, int nrows) {
  int lane = threadIdx.x & 63;
  int wid = (blockIdx.x * blockDim.x + threadIdx.x) >> 6;
  if (wid >= nrows) return;
  int idx = wid * D + lane;
  float e0 = a0[idx], e1 = a1[idx], e2 = a2[idx], eu = as[idx];
  float vd = v[lane];
  float w0 = wave_sum(e0 * vd);
  float w1 = wave_sum(e1 * vd);
  float w2 = wave_sum(e2 * vd);
  float m = fmaxf(w0, fmaxf(w1, w2));
  float s0 = __expf(w0 - m), s1 = __expf(w1 - m), s2 = __expf(w2 - m);
  float inv = 1.f / (s0 + s1 + s2);
  out[idx] = (s0 * e0 + s1 * e1 + s2 * e2) * inv + 0.5f * eu;
}

// acc += x / max(||x_row||, eps)   (fallback path only)
__global__ __launch_bounds__(256) void l2acc_kernel(const float* __restrict__ x,
                                                    float* __restrict__ acc,
                                                    int nrows) {
  int lane = threadIdx.x & 63;
  int wid = (blockIdx.x * blockDim.x + threadIdx.x) >> 6;
  if (wid >= nrows) return;
  int idx = wid * D + lane;
  float xv = x[idx];
  float ss = wave_sum(xv * xv);
  float nrm = fmaxf(sqrtf(ss), EPS);
  acc[idx] += xv / nrm;
}

// out[row[e], :] += val[e] * x[col[e], :]  (fallback atomic scatter)
__global__ __launch_bounds__(256) void spmm_atomic_kernel(
    const int* __restrict__ row, const int* __restrict__ col,
    const float* __restrict__ val, const float* __restrict__ x,
    float* __restrict__ out, int nnz) {
  int lane = threadIdx.x & 63;
  int wid = (blockIdx.x * blockDim.x + threadIdx.x) >> 6;
  int nw = (gridDim.x * blockDim.x) >> 6;
  for (int base = wid * 64; base < nnz; base += nw * 64) {
    int e = base + lane;
    int r = 0, c = 0;
    float v = 0.f;
    if (e < nnz) { r = row[e]; c = col[e]; v = val[e]; }
    int cnt = nnz - base; if (cnt > 64) cnt = 64;
    for (int i = 0; i < cnt; ++i) {
      int ri = __shfl(r, i, 64);
      int ci = __shfl(c, i, 64);
      float vi = __shfl(v, i, 64);
      float xv = x[ci * D + lane];
      atomicAdd(&out[ri * D + lane], vi * xv);
    }
  }
}

// ---------------- CSR build ----------------

__global__ __launch_bounds__(256) void hist_kernel(const int* __restrict__ row,
                                                   int* __restrict__ counts,
                                                   int nnz) {
  int i = blockIdx.x * blockDim.x + threadIdx.x;
  int n = gridDim.x * blockDim.x;
  for (; i < nnz; i += n) atomicAdd(&counts[row[i]], 1);
}

// per-block exclusive scan of 2048 ints; block totals -> partials
__global__ __launch_bounds__(256) void scan1_kernel(const int* __restrict__ in,
                                                    int* __restrict__ out,
                                                    int* __restrict__ partials,
                                                    int n) {
  __shared__ int lds[256];
  int t = threadIdx.x;
  int base = blockIdx.x * 2048 + t * 8;
  int v[8];
  int s = 0;
#pragma unroll
  for (int k = 0; k < 8; ++k) {
    int i = base + k;
    v[k] = (i < n) ? in[i] : 0;
    s += v[k];
  }
  lds[t] = s;
  __syncthreads();
  for (int ofs = 1; ofs < 256; ofs <<= 1) {
    int add = 0;
    if (t >= ofs) add = lds[t - ofs];
    __syncthreads();
    if (t >= ofs) lds[t] += add;
    __syncthreads();
  }
  int excl = lds[t] - s;
  if (t == 255) partials[blockIdx.x] = lds[255];
  int run = excl;
#pragma unroll
  for (int k = 0; k < 8; ++k) {
    int i = base + k;
    if (i < n) out[i] = run;
    run += v[k];
  }
}

// exclusive scan of P (<=256) partials, in place
__global__ __launch_bounds__(256) void scan2_kernel(int* __restrict__ partials,
                                                    int P) {
  __shared__ int lds[256];
  int t = threadIdx.x;
  int s = (t < P) ? partials[t] : 0;
  lds[t] = s;
  __syncthreads();
  for (int ofs = 1; ofs < 256; ofs <<= 1) {
    int add = 0;
    if (t >= ofs) add = lds[t - ofs];
    __syncthreads();
    if (t >= ofs) lds[t] += add;
    __syncthreads();
  }
  if (t < P) partials[t] = lds[t] - s;
}

__global__ __launch_bounds__(256) void scan3_kernel(
    int* __restrict__ out, const int* __restrict__ partials, int n) {
  int i = blockIdx.x * blockDim.x + threadIdx.x;
  int nt = gridDim.x * blockDim.x;
  for (; i < n; i += nt) out[i] += partials[i >> 11];
}

// scatter edges into CSR order: fill[] pre-initialized to row_ptr[]
__global__ __launch_bounds__(256) void scatter_kernel(
    const int* __restrict__ row, const int* __restrict__ col,
    const float* __restrict__ val, int* __restrict__ fill,
    int* __restrict__ cols_out, float* __restrict__ vals_out, int nnz) {
  int i = blockIdx.x * blockDim.x + threadIdx.x;
  int n = gridDim.x * blockDim.x;
  for (; i < nnz; i += n) {
    int r = row[i];
    int idx = atomicAdd(&fill[r], 1);
    cols_out[idx] = col[i];
    vals_out[idx] = val[i];
  }
}

// ---------------- fused CSR SpMM + l2norm-accumulate ----------------
// out[r,:] = sum_e val[e]*x[col[e],:];  acc[r,:] += out[r,:]/max(||out[r,:]||,eps)
__global__ __launch_bounds__(256) void spmm_csr_l2acc_kernel(
    const int* __restrict__ row_ptr, const int* __restrict__ cols,
    const float* __restrict__ vals, const float* __restrict__ x,
    float* __restrict__ out, float* __restrict__ acc, int nrows) {
  int lane = threadIdx.x & 63;
  int r = (blockIdx.x * blockDim.x + threadIdx.x) >> 6;
  if (r >= nrows) return;
  int start = row_ptr[r], end = row_ptr[r + 1];
  float sum = 0.f;
  for (int j = start; j < end; j += 64) {
    int e = j + lane;
    int c = 0;
    float v = 0.f;
    if (e < end) { c = cols[e]; v = vals[e]; }
    int cnt = end - j;
    if (cnt > 64) cnt = 64;
    for (int i = 0; i < cnt; ++i) {
      int ci = __shfl(c, i, 64);
      float vi = __shfl(v, i, 64);
      sum += vi * x[ci * D + lane];
    }
  }
  int idx = r * D + lane;
  out[idx] = sum;
  float ss = wave_sum(sum * sum);
  float nrm = fmaxf(sqrtf(ss), EPS);
  acc[idx] += sum / nrm;
}

// ---------------- host ----------------

static void build_csr(const int* row, const int* col, const float* val, int nnz,
                      int nrows, int* counts, int* row_ptr, int* partials,
                      int* cols_out, float* vals_out, hipStream_t stream) {
  int n1 = nrows + 1;
  hipMemsetAsync(counts, 0, n1 * sizeof(int), stream);
  hipLaunchKernelGGL(hist_kernel, dim3(1024), dim3(256), 0, stream, row, counts,
                     nnz);
  int nblk = (n1 + 2047) / 2048;
  hipLaunchKernelGGL(scan1_kernel, dim3(nblk), dim3(256), 0, stream, counts,
                     row_ptr, partials, n1);
  hipLaunchKernelGGL(scan2_kernel, dim3(1), dim3(256), 0, stream, partials,
                     nblk);
  hipLaunchKernelGGL(scan3_kernel, dim3(64), dim3(256), 0, stream, row_ptr,
                     partials, n1);
  // reuse counts as fill[]
  hipMemcpyAsync(counts, row_ptr, nrows * sizeof(int), hipMemcpyDeviceToDevice,
                 stream);
  hipLaunchKernelGGL(scatter_kernel, dim3(1024), dim3(256), 0, stream, row, col,
                     val, counts, cols_out, vals_out, nnz);
}

extern "C" void kernel_launch(void* const* d_in, const int* in_sizes, int n_in,
                              void* d_out, int out_size, void* d_ws,
                              size_t ws_size, hipStream_t stream) {
  const float* user_emb = (const float*)d_in[0];
  const float* item_emb = (const float*)d_in[1];
  const float* gating_w = (const float*)d_in[2];
  const float* gating_b = (const float*)d_in[3];
  const float* sgating_w = (const float*)d_in[4];
  const float* sgating_b = (const float*)d_in[5];
  const float* att_mat = (const float*)d_in[6];
  const float* att_agg = (const float*)d_in[7];
  const int* hs_row = (const int*)d_in[8];
  const int* hs_col = (const int*)d_in[9];
  const float* hs_val = (const float*)d_in[10];
  const int* hj_row = (const int*)d_in[11];
  const int* hj_col = (const int*)d_in[12];
  const float* hj_val = (const float*)d_in[13];
  const int* hp_row = (const int*)d_in[14];
  const int* hp_col = (const int*)d_in[15];
  const float* hp_val = (const float*)d_in[16];
  const int* inter_row = (const int*)d_in[17];
  const int* inter_col = (const int*)d_in[18];
  const float* inter_val = (const float*)d_in[19];

  const int U = in_sizes[0] / D;  // 100000
  const int I = in_sizes[1] / D;  // 50000
  const int NH = in_sizes[8];     // 3200000
  const int NI = in_sizes[17];    // 3000000
  const size_t UD = (size_t)U * D;
  const size_t ID = (size_t)I * D;

  float* out = (float*)d_out;
  float* final_user = out;  // also acc_simple storage
  float* acc_item = out + UD;
  float* sg0 = out + UD + ID;  // also acc_c0
  float* sg1 = sg0 + UD;       // also acc_c1
  float* sg2 = sg1 + UD;       // also acc_c2
  float* acc0 = sg0, *acc1 = sg1, *acc2 = sg2, *accS = final_user;

  // ---- workspace bump allocator ----
  char* p = (char*)d_ws;
  auto alloc = [&](size_t bytes) -> void* {
    void* r = (void*)p;
    p += (bytes + 255) & ~(size_t)255;
    return r;
  };
  float* u0 = (float*)alloc(UD * 4);
  float* u1 = (float*)alloc(UD * 4);
  float* u2 = (float*)alloc(UD * 4);
  float* us = (float*)alloc(UD * 4);
  float* mixed = (float*)alloc(UD * 4);
  float* spare = (float*)alloc(UD * 4);
  float* it_a = (float*)alloc(ID * 4);
  float* it_b = (float*)alloc(ID * 4);
  float* v = (float*)alloc(256 * 4);
  int* partials = (int*)alloc(256 * 4);
  // CSR structures
  int* cnt_u = (int*)alloc((U + 2) * 4);   // shared counts/fill buffer (user-rows)
  int* cnt_i = (int*)alloc((I + 2) * 4);   // (item-rows)
  int* rp_hs = (int*)alloc((U + 2) * 4);
  int* rp_hj = (int*)alloc((U + 2) * 4);
  int* rp_hp = (int*)alloc((U + 2) * 4);
  int* rp_iu = (int*)alloc((U + 2) * 4);
  int* rp_ii = (int*)alloc((I + 2) * 4);
  int* cols_hs = (int*)alloc((size_t)NH * 4);
  float* vals_hs = (float*)alloc((size_t)NH * 4);
  int* cols_hj = (int*)alloc((size_t)NH * 4);
  float* vals_hj = (float*)alloc((size_t)NH * 4);
  int* cols_hp = (int*)alloc((size_t)NH * 4);
  float* vals_hp = (float*)alloc((size_t)NH * 4);
  int* cols_iu = (int*)alloc((size_t)NI * 4);
  float* vals_iu = (float*)alloc((size_t)NI * 4);
  int* cols_ii = (int*)alloc((size_t)NI * 4);
  float* vals_ii = (float*)alloc((size_t)NI * 4);
  size_t needed = (size_t)(p - (char*)d_ws);
  bool use_csr = needed <= ws_size;

  const int ROWB_U = (U + 3) / 4;  // wave-per-row blocks (256 thr = 4 waves)
  const int ROWB_I = (I + 3) / 4;
  const int SPMM_BLOCKS = 2048;

  // v = att_mat @ att_agg^T
  hipLaunchKernelGGL(compute_v_kernel, dim3(1), dim3(64), 0, stream, att_mat,
                     att_agg, v);
  // self-gating (4 channels) + init accs
  hipLaunchKernelGGL(gating4_kernel, dim3(512), dim3(256), 0, stream, user_emb,
                     gating_w, gating_b, u0, u1, u2, us, acc0, acc1, acc2, accS,
                     U);
  hipMemcpyAsync(acc_item, item_emb, ID * sizeof(float),
                 hipMemcpyDeviceToDevice, stream);
  hipMemcpyAsync(it_a, item_emb, ID * sizeof(float), hipMemcpyDeviceToDevice,
                 stream);

  if (use_csr) {
    build_csr(hs_row, hs_col, hs_val, NH, U, cnt_u, rp_hs, partials, cols_hs,
              vals_hs, stream);
    build_csr(hj_row, hj_col, hj_val, NH, U, cnt_u, rp_hj, partials, cols_hj,
              vals_hj, stream);
    build_csr(hp_row, hp_col, hp_val, NH, U, cnt_u, rp_hp, partials, cols_hp,
              vals_hp, stream);
    build_csr(inter_row, inter_col, inter_val, NI, U, cnt_u, rp_iu, partials,
              cols_iu, vals_iu, stream);
    build_csr(inter_col, inter_row, inter_val, NI, I, cnt_i, rp_ii, partials,
              cols_ii, vals_ii, stream);
  }

  float* it_old = it_a;
  float* it_new = it_b;

  for (int layer = 0; layer < 2; ++layer) {
    hipLaunchKernelGGL(attn_mix_kernel, dim3(ROWB_U), dim3(256), 0, stream, u0,
                       u1, u2, us, v, mixed, U);
    if (use_csr) {
      hipLaunchKernelGGL(spmm_csr_l2acc_kernel, dim3(ROWB_U), dim3(256), 0,
                         stream, rp_hs, cols_hs, vals_hs, u0, spare, acc0, U);
      { float* t = u0; u0 = spare; spare = t; }
      hipLaunchKernelGGL(spmm_csr_l2acc_kernel, dim3(ROWB_U), dim3(256), 0,
                         stream, rp_hj, cols_hj, vals_hj, u1, spare, acc1, U);
      { float* t = u1; u1 = spare; spare = t; }
      hipLaunchKernelGGL(spmm_csr_l2acc_kernel, dim3(ROWB_U), dim3(256), 0,
                         stream, rp_hp, cols_hp, vals_hp, u2, spare, acc2, U);
      { float* t = u2; u2 = spare; spare = t; }
      hipLaunchKernelGGL(spmm_csr_l2acc_kernel, dim3(ROWB_I), dim3(256), 0,
                         stream, rp_ii, cols_ii, vals_ii, mixed, it_new,
                         acc_item, I);
      hipLaunchKernelGGL(spmm_csr_l2acc_kernel, dim3(ROWB_U), dim3(256), 0,
                         stream, rp_iu, cols_iu, vals_iu, it_old, spare, accS,
                         U);
      { float* t = us; us = spare; spare = t; }
    } else {
      hipMemsetAsync(spare, 0, UD * sizeof(float), stream);
      hipLaunchKernelGGL(spmm_atomic_kernel, dim3(SPMM_BLOCKS), dim3(256), 0,
                         stream, hs_row, hs_col, hs_val, u0, spare, NH);
      hipLaunchKernelGGL(l2acc_kernel, dim3(ROWB_U), dim3(256), 0, stream,
                         spare, acc0, U);
      { float* t = u0; u0 = spare; spare = t; }
      hipMemsetAsync(spare, 0, UD * sizeof(float), stream);
      hipLaunchKernelGGL(spmm_atomic_kernel, dim3(SPMM_BLOCKS), dim3(256), 0,
                         stream, hj_row, hj_col, hj_val, u1, spare, NH);
      hipLaunchKernelGGL(l2acc_kernel, dim3(ROWB_U), dim3(256), 0, stream,
                         spare, acc1, U);
      { float* t = u1; u1 = spare; spare = t; }
      hipMemsetAsync(spare, 0, UD * sizeof(float), stream);
      hipLaunchKernelGGL(spmm_atomic_kernel, dim3(SPMM_BLOCKS), dim3(256), 0,
                         stream, hp_row, hp_col, hp_val, u2, spare, NH);
      hipLaunchKernelGGL(l2acc_kernel, dim3(ROWB_U), dim3(256), 0, stream,
                         spare, acc2, U);
      { float* t = u2; u2 = spare; spare = t; }
      hipMemsetAsync(it_new, 0, ID * sizeof(float), stream);
      hipLaunchKernelGGL(spmm_atomic_kernel, dim3(SPMM_BLOCKS), dim3(256), 0,
                         stream, inter_col, inter_row, inter_val, mixed, it_new,
                         NI);
      hipLaunchKernelGGL(l2acc_kernel, dim3(ROWB_I), dim3(256), 0, stream,
                         it_new, acc_item, I);
      hipMemsetAsync(spare, 0, UD * sizeof(float), stream);
      hipLaunchKernelGGL(spmm_atomic_kernel, dim3(SPMM_BLOCKS), dim3(256), 0,
                         stream, inter_row, inter_col, inter_val, it_old, spare,
                         NI);
      hipLaunchKernelGGL(l2acc_kernel, dim3(ROWB_U), dim3(256), 0, stream,
                         spare, accS, U);
      { float* t = us; us = spare; spare = t; }
    }
    { float* t = it_old; it_old = it_new; it_new = t; }
  }

  hipLaunchKernelGGL(final_attn_kernel, dim3(ROWB_U), dim3(256), 0, stream,
                     acc0, acc1, acc2, accS, v, final_user, U);
  hipLaunchKernelGGL(sgating3_kernel, dim3(512), dim3(256), 0, stream,
                     final_user, sgating_w, sgating_b, sg0, sg1, sg2, U);
}

// Round 3
// 3711.751 us; speedup vs baseline: 1.9928x; 1.1858x over previous
//
#include <hip/hip_runtime.h>

#define D 64
#define EPS 1e-12f

__device__ __forceinline__ float wave_sum(float v) {
#pragma unroll
  for (int off = 32; off > 0; off >>= 1) v += __shfl_xor(v, off, 64);
  return v;
}

// v[d] = sum_j att_mat[d, j] * att_agg[j]
__global__ void compute_v_kernel(const float* __restrict__ att_mat,
                                 const float* __restrict__ att_agg,
                                 float* __restrict__ v) {
  int d = threadIdx.x;
  float s = 0.f;
#pragma unroll
  for (int j = 0; j < D; ++j) s += att_mat[d * D + j] * att_agg[j];
  v[d] = s;
}

// u_k = emb * sigmoid(emb @ W_k + b_k) for k=0..3 ; also write copies to acc slots
__global__ __launch_bounds__(256) void gating4_kernel(
    const float* __restrict__ emb, const float* __restrict__ W,
    const float* __restrict__ B, float* __restrict__ u0, float* __restrict__ u1,
    float* __restrict__ u2, float* __restrict__ u3, float* __restrict__ a0,
    float* __restrict__ a1, float* __restrict__ a2, float* __restrict__ a3,
    int nrows) {
  __shared__ float sW[4 * D * D];  // 64 KiB
  for (int i = threadIdx.x; i < 4 * D * D; i += blockDim.x) sW[i] = W[i];
  __syncthreads();
  int lane = threadIdx.x & 63;
  int wid = (blockIdx.x * blockDim.x + threadIdx.x) >> 6;
  int nw = (gridDim.x * blockDim.x) >> 6;
  float b0 = B[0 * D + lane], b1 = B[1 * D + lane];
  float b2 = B[2 * D + lane], b3 = B[3 * D + lane];
  for (int r = wid; r < nrows; r += nw) {
    float e = emb[r * D + lane];
    float y0 = b0, y1 = b1, y2 = b2, y3 = b3;
#pragma unroll 16
    for (int j = 0; j < D; ++j) {
      float ej = __shfl(e, j, 64);
      y0 += ej * sW[0 * D * D + j * D + lane];
      y1 += ej * sW[1 * D * D + j * D + lane];
      y2 += ej * sW[2 * D * D + j * D + lane];
      y3 += ej * sW[3 * D * D + j * D + lane];
    }
    float o0 = e / (1.f + __expf(-y0));
    float o1 = e / (1.f + __expf(-y1));
    float o2 = e / (1.f + __expf(-y2));
    float o3 = e / (1.f + __expf(-y3));
    int idx = r * D + lane;
    u0[idx] = o0; a0[idx] = o0;
    u1[idx] = o1; a1[idx] = o1;
    u2[idx] = o2; a2[idx] = o2;
    u3[idx] = o3; a3[idx] = o3;
  }
}

// sg_k = x * sigmoid(x @ W_k + b_k) for k=0..2
__global__ __launch_bounds__(256) void sgating3_kernel(
    const float* __restrict__ x, const float* __restrict__ W,
    const float* __restrict__ B, float* __restrict__ o0f,
    float* __restrict__ o1f, float* __restrict__ o2f, int nrows) {
  __shared__ float sW[3 * D * D];  // 48 KiB
  for (int i = threadIdx.x; i < 3 * D * D; i += blockDim.x) sW[i] = W[i];
  __syncthreads();
  int lane = threadIdx.x & 63;
  int wid = (blockIdx.x * blockDim.x + threadIdx.x) >> 6;
  int nw = (gridDim.x * blockDim.x) >> 6;
  float b0 = B[0 * D + lane], b1 = B[1 * D + lane], b2 = B[2 * D + lane];
  for (int r = wid; r < nrows; r += nw) {
    float e = x[r * D + lane];
    float y0 = b0, y1 = b1, y2 = b2;
#pragma unroll 16
    for (int j = 0; j < D; ++j) {
      float ej = __shfl(e, j, 64);
      y0 += ej * sW[0 * D * D + j * D + lane];
      y1 += ej * sW[1 * D * D + j * D + lane];
      y2 += ej * sW[2 * D * D + j * D + lane];
    }
    int idx = r * D + lane;
    o0f[idx] = e / (1.f + __expf(-y0));
    o1f[idx] = e / (1.f + __expf(-y1));
    o2f[idx] = e / (1.f + __expf(-y2));
  }
}

// mixed = (softmax-weighted(u0,u1,u2) + us) * 0.5
__global__ __launch_bounds__(256) void attn_mix_kernel(
    const float* __restrict__ u0, const float* __restrict__ u1,
    const float* __restrict__ u2, const float* __restrict__ us,
    const float* __restrict__ v, float* __restrict__ mixed, int nrows) {
  int lane = threadIdx.x & 63;
  int wid = (blockIdx.x * blockDim.x + threadIdx.x) >> 6;
  if (wid >= nrows) return;
  int idx = wid * D + lane;
  float e0 = u0[idx], e1 = u1[idx], e2 = u2[idx], eu = us[idx];
  float vd = v[lane];
  float w0 = wave_sum(e0 * vd);
  float w1 = wave_sum(e1 * vd);
  float w2 = wave_sum(e2 * vd);
  float m = fmaxf(w0, fmaxf(w1, w2));
  float s0 = __expf(w0 - m), s1 = __expf(w1 - m), s2 = __expf(w2 - m);
  float inv = 1.f / (s0 + s1 + s2);
  mixed[idx] = ((s0 * e0 + s1 * e1 + s2 * e2) * inv + eu) * 0.5f;
}

// out = softmax-weighted(a0,a1,a2) + 0.5*as  (as may alias out; per-element safe)
__global__ __launch_bounds__(256) void final_attn_kernel(
    const float* __restrict__ a0, const float* __restrict__ a1,
    const float* __restrict__ a2, const float* __restrict__ as,
    const float* __restrict__ v, float* __restrict__ out, int nrows) {
  int lane = threadIdx.x & 63;
  int wid = (blockIdx.x * blockDim.x + threadIdx.x) >> 6;
  if (wid >= nrows) return;
  int idx = wid * D + lane;
  float e0 = a0[idx], e1 = a1[idx], e2 = a2[idx], eu = as[idx];
  float vd = v[lane];
  float w0 = wave_sum(e0 * vd);
  float w1 = wave_sum(e1 * vd);
  float w2 = wave_sum(e2 * vd);
  float m = fmaxf(w0, fmaxf(w1, w2));
  float s0 = __expf(w0 - m), s1 = __expf(w1 - m), s2 = __expf(w2 - m);
  float inv = 1.f / (s0 + s1 + s2);
  out[idx] = (s0 * e0 + s1 * e1 + s2 * e2) * inv + 0.5f * eu;
}

// acc += x / max(||x_row||, eps)   (fallback path only)
__global__ __launch_bounds__(256) void l2acc_kernel(const float* __restrict__ x,
                                                    float* __restrict__ acc,
                                                    int nrows) {
  int lane = threadIdx.x & 63;
  int wid = (blockIdx.x * blockDim.x + threadIdx.x) >> 6;
  if (wid >= nrows) return;
  int idx = wid * D + lane;
  float xv = x[idx];
  float ss = wave_sum(xv * xv);
  float nrm = fmaxf(sqrtf(ss), EPS);
  acc[idx] += xv / nrm;
}

// out[row[e], :] += val[e] * x[col[e], :]  (fallback atomic scatter)
__global__ __launch_bounds__(256) void spmm_atomic_kernel(
    const int* __restrict__ row, const int* __restrict__ col,
    const float* __restrict__ val, const float* __restrict__ x,
    float* __restrict__ out, int nnz) {
  int lane = threadIdx.x & 63;
  int wid = (blockIdx.x * blockDim.x + threadIdx.x) >> 6;
  int nw = (gridDim.x * blockDim.x) >> 6;
  for (int base = wid * 64; base < nnz; base += nw * 64) {
    int e = base + lane;
    int r = 0, c = 0;
    float v = 0.f;
    if (e < nnz) { r = row[e]; c = col[e]; v = val[e]; }
    int cnt = nnz - base; if (cnt > 64) cnt = 64;
    for (int i = 0; i < cnt; ++i) {
      int ri = __shfl(r, i, 64);
      int ci = __shfl(c, i, 64);
      float vi = __shfl(v, i, 64);
      float xv = x[ci * D + lane];
      atomicAdd(&out[ri * D + lane], vi * xv);
    }
  }
}

// ---------------- CSR build ----------------

__global__ __launch_bounds__(256) void hist_kernel(const int* __restrict__ row,
                                                   int* __restrict__ counts,
                                                   int nnz) {
  int i = blockIdx.x * blockDim.x + threadIdx.x;
  int n = gridDim.x * blockDim.x;
  for (; i < nnz; i += n) atomicAdd(&counts[row[i]], 1);
}

// per-block exclusive scan of 2048 ints; block totals -> partials
__global__ __launch_bounds__(256) void scan1_kernel(const int* __restrict__ in,
                                                    int* __restrict__ out,
                                                    int* __restrict__ partials,
                                                    int n) {
  __shared__ int lds[256];
  int t = threadIdx.x;
  int base = blockIdx.x * 2048 + t * 8;
  int v[8];
  int s = 0;
#pragma unroll
  for (int k = 0; k < 8; ++k) {
    int i = base + k;
    v[k] = (i < n) ? in[i] : 0;
    s += v[k];
  }
  lds[t] = s;
  __syncthreads();
  for (int ofs = 1; ofs < 256; ofs <<= 1) {
    int add = 0;
    if (t >= ofs) add = lds[t - ofs];
    __syncthreads();
    if (t >= ofs) lds[t] += add;
    __syncthreads();
  }
  int excl = lds[t] - s;
  if (t == 255) partials[blockIdx.x] = lds[255];
  int run = excl;
#pragma unroll
  for (int k = 0; k < 8; ++k) {
    int i = base + k;
    if (i < n) out[i] = run;
    run += v[k];
  }
}

// exclusive scan of P (<=256) partials, in place
__global__ __launch_bounds__(256) void scan2_kernel(int* __restrict__ partials,
                                                    int P) {
  __shared__ int lds[256];
  int t = threadIdx.x;
  int s = (t < P) ? partials[t] : 0;
  lds[t] = s;
  __syncthreads();
  for (int ofs = 1; ofs < 256; ofs <<= 1) {
    int add = 0;
    if (t >= ofs) add = lds[t - ofs];
    __syncthreads();
    if (t >= ofs) lds[t] += add;
    __syncthreads();
  }
  if (t < P) partials[t] = lds[t] - s;
}

__global__ __launch_bounds__(256) void scan3_kernel(
    int* __restrict__ out, const int* __restrict__ partials, int n) {
  int i = blockIdx.x * blockDim.x + threadIdx.x;
  int nt = gridDim.x * blockDim.x;
  for (; i < n; i += nt) out[i] += partials[i >> 11];
}

// scatter edges into CSR order as packed (col, val_bits) int2 — single 8 B
// store per edge touches ONE random cache line (was two with split arrays)
__global__ __launch_bounds__(256) void scatter_kernel(
    const int* __restrict__ row, const int* __restrict__ col,
    const float* __restrict__ val, int* __restrict__ fill,
    int2* __restrict__ edges_out, int nnz) {
  int i = blockIdx.x * blockDim.x + threadIdx.x;
  int n = gridDim.x * blockDim.x;
  for (; i < nnz; i += n) {
    int r = row[i];
    int idx = atomicAdd(&fill[r], 1);
    edges_out[idx] = make_int2(col[i], __float_as_int(val[i]));
  }
}

// ---------------- fused CSR SpMM + l2norm-accumulate ----------------
// out[r,:] = sum_e val[e]*x[col[e],:];  acc[r,:] += out[r,:]/max(||out[r,:]||,eps)
// 4-deep gather pipelining: 4 independent x-row loads in flight per wave.
__global__ __launch_bounds__(256) void spmm_csr_l2acc_kernel(
    const int* __restrict__ row_ptr, const int2* __restrict__ edges,
    const float* __restrict__ x, float* __restrict__ out,
    float* __restrict__ acc, int nrows) {
  int lane = threadIdx.x & 63;
  int r = (blockIdx.x * blockDim.x + threadIdx.x) >> 6;
  if (r >= nrows) return;
  int start = row_ptr[r], end = row_ptr[r + 1];
  float sum = 0.f;
  for (int j = start; j < end; j += 64) {
    int e = j + lane;
    int c = 0;
    float v = 0.f;
    if (e < end) {
      int2 ev = edges[e];
      c = ev.x;
      v = __int_as_float(ev.y);
    }
    int cnt = end - j;
    if (cnt > 64) cnt = 64;
    int i = 0;
    for (; i + 4 <= cnt; i += 4) {
      int c0 = __shfl(c, i, 64);
      int c1 = __shfl(c, i + 1, 64);
      int c2 = __shfl(c, i + 2, 64);
      int c3 = __shfl(c, i + 3, 64);
      float v0 = __shfl(v, i, 64);
      float v1 = __shfl(v, i + 1, 64);
      float v2 = __shfl(v, i + 2, 64);
      float v3 = __shfl(v, i + 3, 64);
      float x0 = x[c0 * D + lane];
      float x1 = x[c1 * D + lane];
      float x2 = x[c2 * D + lane];
      float x3 = x[c3 * D + lane];
      sum += v0 * x0;
      sum += v1 * x1;
      sum += v2 * x2;
      sum += v3 * x3;
    }
    for (; i < cnt; ++i) {
      int ci = __shfl(c, i, 64);
      float vi = __shfl(v, i, 64);
      sum += vi * x[ci * D + lane];
    }
  }
  int idx = r * D + lane;
  out[idx] = sum;
  float ss = wave_sum(sum * sum);
  float nrm = fmaxf(sqrtf(ss), EPS);
  acc[idx] += sum / nrm;
}

// ---------------- host ----------------

static void build_csr(const int* row, const int* col, const float* val, int nnz,
                      int nrows, int* counts, int* row_ptr, int* partials,
                      int2* edges_out, hipStream_t stream) {
  int n1 = nrows + 1;
  hipMemsetAsync(counts, 0, n1 * sizeof(int), stream);
  hipLaunchKernelGGL(hist_kernel, dim3(1024), dim3(256), 0, stream, row, counts,
                     nnz);
  int nblk = (n1 + 2047) / 2048;
  hipLaunchKernelGGL(scan1_kernel, dim3(nblk), dim3(256), 0, stream, counts,
                     row_ptr, partials, n1);
  hipLaunchKernelGGL(scan2_kernel, dim3(1), dim3(256), 0, stream, partials,
                     nblk);
  hipLaunchKernelGGL(scan3_kernel, dim3(64), dim3(256), 0, stream, row_ptr,
                     partials, n1);
  // reuse counts as fill[]
  hipMemcpyAsync(counts, row_ptr, nrows * sizeof(int), hipMemcpyDeviceToDevice,
                 stream);
  hipLaunchKernelGGL(scatter_kernel, dim3(1024), dim3(256), 0, stream, row, col,
                     val, counts, edges_out, nnz);
}

extern "C" void kernel_launch(void* const* d_in, const int* in_sizes, int n_in,
                              void* d_out, int out_size, void* d_ws,
                              size_t ws_size, hipStream_t stream) {
  const float* user_emb = (const float*)d_in[0];
  const float* item_emb = (const float*)d_in[1];
  const float* gating_w = (const float*)d_in[2];
  const float* gating_b = (const float*)d_in[3];
  const float* sgating_w = (const float*)d_in[4];
  const float* sgating_b = (const float*)d_in[5];
  const float* att_mat = (const float*)d_in[6];
  const float* att_agg = (const float*)d_in[7];
  const int* hs_row = (const int*)d_in[8];
  const int* hs_col = (const int*)d_in[9];
  const float* hs_val = (const float*)d_in[10];
  const int* hj_row = (const int*)d_in[11];
  const int* hj_col = (const int*)d_in[12];
  const float* hj_val = (const float*)d_in[13];
  const int* hp_row = (const int*)d_in[14];
  const int* hp_col = (const int*)d_in[15];
  const float* hp_val = (const float*)d_in[16];
  const int* inter_row = (const int*)d_in[17];
  const int* inter_col = (const int*)d_in[18];
  const float* inter_val = (const float*)d_in[19];

  const int U = in_sizes[0] / D;  // 100000
  const int I = in_sizes[1] / D;  // 50000
  const int NH = in_sizes[8];     // 3200000
  const int NI = in_sizes[17];    // 3000000
  const size_t UD = (size_t)U * D;
  const size_t ID = (size_t)I * D;

  float* out = (float*)d_out;
  float* final_user = out;  // also acc_simple storage
  float* acc_item = out + UD;
  float* sg0 = out + UD + ID;  // also acc_c0
  float* sg1 = sg0 + UD;       // also acc_c1
  float* sg2 = sg1 + UD;       // also acc_c2
  float* acc0 = sg0, *acc1 = sg1, *acc2 = sg2, *accS = final_user;

  // ---- workspace bump allocator ----
  char* p = (char*)d_ws;
  auto alloc = [&](size_t bytes) -> void* {
    void* r = (void*)p;
    p += (bytes + 255) & ~(size_t)255;
    return r;
  };
  float* u0 = (float*)alloc(UD * 4);
  float* u1 = (float*)alloc(UD * 4);
  float* u2 = (float*)alloc(UD * 4);
  float* us = (float*)alloc(UD * 4);
  float* mixed = (float*)alloc(UD * 4);
  float* spare = (float*)alloc(UD * 4);
  float* it_a = (float*)alloc(ID * 4);
  float* it_b = (float*)alloc(ID * 4);
  float* v = (float*)alloc(256 * 4);
  int* partials = (int*)alloc(256 * 4);
  // CSR structures
  int* cnt_u = (int*)alloc((U + 2) * 4);  // shared counts/fill buffer (user)
  int* cnt_i = (int*)alloc((I + 2) * 4);  // (item)
  int* rp_hs = (int*)alloc((U + 2) * 4);
  int* rp_hj = (int*)alloc((U + 2) * 4);
  int* rp_hp = (int*)alloc((U + 2) * 4);
  int* rp_iu = (int*)alloc((U + 2) * 4);
  int* rp_ii = (int*)alloc((I + 2) * 4);
  int2* ed_hs = (int2*)alloc((size_t)NH * 8);
  int2* ed_hj = (int2*)alloc((size_t)NH * 8);
  int2* ed_hp = (int2*)alloc((size_t)NH * 8);
  int2* ed_iu = (int2*)alloc((size_t)NI * 8);
  int2* ed_ii = (int2*)alloc((size_t)NI * 8);
  size_t needed = (size_t)(p - (char*)d_ws);
  bool use_csr = needed <= ws_size;

  const int ROWB_U = (U + 3) / 4;  // wave-per-row blocks (256 thr = 4 waves)
  const int ROWB_I = (I + 3) / 4;
  const int SPMM_BLOCKS = 2048;

  // v = att_mat @ att_agg^T
  hipLaunchKernelGGL(compute_v_kernel, dim3(1), dim3(64), 0, stream, att_mat,
                     att_agg, v);
  // self-gating (4 channels) + init accs
  hipLaunchKernelGGL(gating4_kernel, dim3(512), dim3(256), 0, stream, user_emb,
                     gating_w, gating_b, u0, u1, u2, us, acc0, acc1, acc2, accS,
                     U);
  hipMemcpyAsync(acc_item, item_emb, ID * sizeof(float),
                 hipMemcpyDeviceToDevice, stream);
  hipMemcpyAsync(it_a, item_emb, ID * sizeof(float), hipMemcpyDeviceToDevice,
                 stream);

  if (use_csr) {
    build_csr(hs_row, hs_col, hs_val, NH, U, cnt_u, rp_hs, partials, ed_hs,
              stream);
    build_csr(hj_row, hj_col, hj_val, NH, U, cnt_u, rp_hj, partials, ed_hj,
              stream);
    build_csr(hp_row, hp_col, hp_val, NH, U, cnt_u, rp_hp, partials, ed_hp,
              stream);
    build_csr(inter_row, inter_col, inter_val, NI, U, cnt_u, rp_iu, partials,
              ed_iu, stream);
    build_csr(inter_col, inter_row, inter_val, NI, I, cnt_i, rp_ii, partials,
              ed_ii, stream);
  }

  float* it_old = it_a;
  float* it_new = it_b;

  for (int layer = 0; layer < 2; ++layer) {
    hipLaunchKernelGGL(attn_mix_kernel, dim3(ROWB_U), dim3(256), 0, stream, u0,
                       u1, u2, us, v, mixed, U);
    if (use_csr) {
      hipLaunchKernelGGL(spmm_csr_l2acc_kernel, dim3(ROWB_U), dim3(256), 0,
                         stream, rp_hs, ed_hs, u0, spare, acc0, U);
      { float* t = u0; u0 = spare; spare = t; }
      hipLaunchKernelGGL(spmm_csr_l2acc_kernel, dim3(ROWB_U), dim3(256), 0,
                         stream, rp_hj, ed_hj, u1, spare, acc1, U);
      { float* t = u1; u1 = spare; spare = t; }
      hipLaunchKernelGGL(spmm_csr_l2acc_kernel, dim3(ROWB_U), dim3(256), 0,
                         stream, rp_hp, ed_hp, u2, spare, acc2, U);
      { float* t = u2; u2 = spare; spare = t; }
      hipLaunchKernelGGL(spmm_csr_l2acc_kernel, dim3(ROWB_I), dim3(256), 0,
                         stream, rp_ii, ed_ii, mixed, it_new, acc_item, I);
      hipLaunchKernelGGL(spmm_csr_l2acc_kernel, dim3(ROWB_U), dim3(256), 0,
                         stream, rp_iu, ed_iu, it_old, spare, accS, U);
      { float* t = us; us = spare; spare = t; }
    } else {
      hipMemsetAsync(spare, 0, UD * sizeof(float), stream);
      hipLaunchKernelGGL(spmm_atomic_kernel, dim3(SPMM_BLOCKS), dim3(256), 0,
                         stream, hs_row, hs_col, hs_val, u0, spare, NH);
      hipLaunchKernelGGL(l2acc_kernel, dim3(ROWB_U), dim3(256), 0, stream,
                         spare, acc0, U);
      { float* t = u0; u0 = spare; spare = t; }
      hipMemsetAsync(spare, 0, UD * sizeof(float), stream);
      hipLaunchKernelGGL(spmm_atomic_kernel, dim3(SPMM_BLOCKS), dim3(256), 0,
                         stream, hj_row, hj_col, hj_val, u1, spare, NH);
      hipLaunchKernelGGL(l2acc_kernel, dim3(ROWB_U), dim3(256), 0, stream,
                         spare, acc1, U);
      { float* t = u1; u1 = spare; spare = t; }
      hipMemsetAsync(spare, 0, UD * sizeof(float), stream);
      hipLaunchKernelGGL(spmm_atomic_kernel, dim3(SPMM_BLOCKS), dim3(256), 0,
                         stream, hp_row, hp_col, hp_val, u2, spare, NH);
      hipLaunchKernelGGL(l2acc_kernel, dim3(ROWB_U), dim3(256), 0, stream,
                         spare, acc2, U);
      { float* t = u2; u2 = spare; spare = t; }
      hipMemsetAsync(it_new, 0, ID * sizeof(float), stream);
      hipLaunchKernelGGL(spmm_atomic_kernel, dim3(SPMM_BLOCKS), dim3(256), 0,
                         stream, inter_col, inter_row, inter_val, mixed, it_new,
                         NI);
      hipLaunchKernelGGL(l2acc_kernel, dim3(ROWB_I), dim3(256), 0, stream,
                         it_new, acc_item, I);
      hipMemsetAsync(spare, 0, UD * sizeof(float), stream);
      hipLaunchKernelGGL(spmm_atomic_kernel, dim3(SPMM_BLOCKS), dim3(256), 0,
                         stream, inter_row, inter_col, inter_val, it_old, spare,
                         NI);
      hipLaunchKernelGGL(l2acc_kernel, dim3(ROWB_U), dim3(256), 0, stream,
                         spare, accS, U);
      { float* t = us; us = spare; spare = t; }
    }
    { float* t = it_old; it_old = it_new; it_new = t; }
  }

  hipLaunchKernelGGL(final_attn_kernel, dim3(ROWB_U), dim3(256), 0, stream,
                     acc0, acc1, acc2, accS, v, final_user, U);
  hipLaunchKernelGGL(sgating3_kernel, dim3(512), dim3(256), 0, stream,
                     final_user, sgating_w, sgating_b, sg0, sg1, sg2, U);
}